// Round 7
// baseline (434.411 us; speedup 1.0000x reference)
//
#include <hip/hip_runtime.h>
#include <hip/hip_bf16.h>

typedef float f32x4 __attribute__((ext_vector_type(4)));
typedef __bf16 bf16x8 __attribute__((ext_vector_type(8)));

#define NNODES 50000
#define NEDGES 800000
#define FIN 128
#define FHID 384
#define FOUT 256

// scan geometry: 49 blocks x 256 threads x 4 elements
#define SCAN_NB ((NNODES + 1023) / 1024)

// histogram geometry: 64 blocks, packed 2xu16 counts for all 50000 nodes in LDS
#define HB 64
#define EPB (NEDGES / HB)   // 12500 edges per hist block
#define HW (NNODES / 2)     // 25000 u32 words (2 nodes/word)

__device__ __forceinline__ float bf_lo(unsigned u) { return __uint_as_float(u << 16); }
__device__ __forceinline__ float bf_hi(unsigned u) { return __uint_as_float(u & 0xffff0000u); }
__device__ __forceinline__ unsigned short f2bf(float f) {
  unsigned u = __float_as_uint(f);
  u += 0x7fffu + ((u >> 16) & 1u);
  return (unsigned short)(u >> 16);
}

// ---------- feature f32 -> bf16, prescaled by out_norm[row] ----------
__global__ void cvt_feat_kernel(const float* __restrict__ f,
                                const float* __restrict__ onorm,
                                unsigned short* __restrict__ o, int n4) {
  int i = blockIdx.x * blockDim.x + threadIdx.x;
  if (i >= n4) return;
  float4 v = *(const float4*)(f + (size_t)i * 4);
  float w = onorm[(i * 4) >> 7];  // row = (i*4)/FIN
  ushort4 r;
  r.x = f2bf(v.x * w); r.y = f2bf(v.y * w);
  r.z = f2bf(v.z * w); r.w = f2bf(v.w * w);
  *(ushort4*)(o + (size_t)i * 4) = r;
}

// ---------- W [K][Nw] f32 -> Wt [Nw][K] bf16 ----------
__global__ void wt_kernel(const float* __restrict__ W, __bf16* __restrict__ Wt, int K, int Nw) {
  int i = blockIdx.x * blockDim.x + threadIdx.x;
  if (i >= K * Nw) return;
  int k = i / Nw, n = i % Nw;
  unsigned short b = f2bf(W[i]);
  Wt[(size_t)n * K + k] = *(__bf16*)&b;
}

// ---------- LDS histogram of node occurrences (no global atomics) ----------
// grid (HB, 2): y=0 counts src -> psrc partials; y=1 counts dst -> pdst partials + per-edge rank
__global__ __launch_bounds__(256) void hist_kernel(
    const int* __restrict__ ei, unsigned* __restrict__ psrc,
    unsigned* __restrict__ pdst, unsigned short* __restrict__ rank) {
  __shared__ unsigned hist[HW];
  int b = blockIdx.x, pass = blockIdx.y, t = threadIdx.x;
  for (int i = t; i < HW; i += 256) hist[i] = 0;
  __syncthreads();
  const int* idx = ei + (pass ? NEDGES : 0) + b * EPB;
  if (pass == 0) {
    for (int i = t; i < EPB; i += 256) {
      int n = idx[i];
      atomicAdd(&hist[n >> 1], 1u << ((n & 1) << 4));
    }
  } else {
    for (int i = t; i < EPB; i += 256) {
      int n = idx[i];
      unsigned sh = (n & 1) << 4;
      unsigned old = atomicAdd(&hist[n >> 1], 1u << sh);
      rank[b * EPB + i] = (unsigned short)((old >> sh) & 0xFFFFu);
    }
  }
  __syncthreads();
  unsigned* dst = (pass ? pdst : psrc) + (size_t)b * HW;
  for (int i = t; i < HW; i += 256) dst[i] = hist[i];
}

// ---------- reduce partials -> degrees + norms; convert pdst to per-block exclusive prefixes ----------
__global__ __launch_bounds__(256) void reduce_hist(
    const unsigned* __restrict__ psrc, unsigned* __restrict__ pdst,
    int* __restrict__ din, float* __restrict__ onorm, float* __restrict__ inorm) {
  int w = blockIdx.x * blockDim.x + threadIdx.x;
  if (w >= HW) return;
  unsigned sl = 0, sh = 0;
#pragma unroll 8
  for (int b = 0; b < HB; ++b) {
    unsigned v = psrc[(size_t)b * HW + w];
    sl += v & 0xFFFFu; sh += v >> 16;
  }
  unsigned rl = 0, rh = 0;
#pragma unroll 8
  for (int b = 0; b < HB; ++b) {
    size_t o = (size_t)b * HW + w;
    unsigned v = pdst[o];
    pdst[o] = rl | (rh << 16);  // exclusive prefix over blocks, packed 2xu16
    rl += v & 0xFFFFu; rh += v >> 16;
  }
  int n0 = 2 * w, n1 = 2 * w + 1;
  din[n0] = (int)rl; din[n1] = (int)rh;
  onorm[n0] = rsqrtf((float)(sl ? sl : 1u));
  onorm[n1] = rsqrtf((float)(sh ? sh : 1u));
  inorm[n0] = rsqrtf((float)(rl ? rl : 1u));
  inorm[n1] = rsqrtf((float)(rh ? rh : 1u));
}

// ---------- multi-block exclusive scan, stage 1: per-block sums ----------
__global__ __launch_bounds__(256) void scan_part1(const int* __restrict__ deg,
                                                  int* __restrict__ blocksums) {
  int b = blockIdx.x, t = threadIdx.x;
  int base = b * 1024 + t * 4;
  int s = 0;
  if (base + 4 <= NNODES) {
    int4 v = *(const int4*)(deg + base);
    s = v.x + v.y + v.z + v.w;
  } else {
    for (int j = 0; j < 4; ++j)
      if (base + j < NNODES) s += deg[base + j];
  }
  for (int d = 32; d >= 1; d >>= 1) s += __shfl_down(s, d, 64);
  __shared__ int ws[4];
  int lane = t & 63, w = t >> 6;
  if (lane == 0) ws[w] = s;
  __syncthreads();
  if (t == 0) blocksums[b] = ws[0] + ws[1] + ws[2] + ws[3];
}

// ---------- stage 2: one wave scans the block sums (SCAN_NB <= 64) ----------
__global__ void scan_mid(const int* __restrict__ bs, int* __restrict__ boff) {
  int t = threadIdx.x;  // 64 threads
  int v = (t < SCAN_NB) ? bs[t] : 0;
  int x = v;
  for (int d = 1; d < 64; d <<= 1) {
    int y = __shfl_up(x, d, 64);
    if (t >= d) x += y;
  }
  if (t < SCAN_NB) boff[t] = x - v;  // exclusive
}

// ---------- stage 3: intra-block exclusive scan + write row_ptr ----------
__global__ __launch_bounds__(256) void scan_part2(const int* __restrict__ deg,
                                                  const int* __restrict__ boff,
                                                  int* __restrict__ row_ptr) {
  int b = blockIdx.x, t = threadIdx.x;
  int base = b * 1024 + t * 4;
  int v0 = 0, v1 = 0, v2 = 0, v3 = 0;
  if (base + 4 <= NNODES) {
    int4 v = *(const int4*)(deg + base);
    v0 = v.x; v1 = v.y; v2 = v.z; v3 = v.w;
  } else {
    if (base + 0 < NNODES) v0 = deg[base + 0];
    if (base + 1 < NNODES) v1 = deg[base + 1];
    if (base + 2 < NNODES) v2 = deg[base + 2];
    if (base + 3 < NNODES) v3 = deg[base + 3];
  }
  int s = v0 + v1 + v2 + v3;
  int x = s;
  int lane = t & 63, w = t >> 6;
  for (int d = 1; d < 64; d <<= 1) {
    int y = __shfl_up(x, d, 64);
    if (lane >= d) x += y;
  }
  __shared__ int ws[4];
  if (lane == 63) ws[w] = x;
  __syncthreads();
  int woff = 0;
  for (int i = 0; i < w; ++i) woff += ws[i];
  int off = boff[b] + woff + (x - s);  // exclusive prefix for this thread
  if (base + 0 < NNODES) { row_ptr[base + 0] = off; off += v0; }
  if (base + 1 < NNODES) { row_ptr[base + 1] = off; off += v1; }
  if (base + 2 < NNODES) { row_ptr[base + 2] = off; off += v2; }
  if (base + 3 < NNODES) { row_ptr[base + 3] = off; off += v3; }
  if (base < NNODES && base + 4 >= NNODES) row_ptr[NNODES] = off;
}

// ---------- CSR fill, atomic-free: pos = row_ptr[dst] + prefix[b][dst] + rank[e] ----------
__global__ void fill_kernel(const int* __restrict__ ei,
                            const unsigned short* __restrict__ rank,
                            const unsigned* __restrict__ pdst,
                            const int* __restrict__ row_ptr,
                            int* __restrict__ csr) {
  int e = blockIdx.x * blockDim.x + threadIdx.x;
  if (e >= NEDGES) return;
  int n = ei[NEDGES + e];
  int b = e / EPB;  // which hist block counted this edge
  unsigned base = (pdst[(size_t)b * HW + (n >> 1)] >> ((n & 1) << 4)) & 0xFFFFu;
  csr[row_ptr[n] + (int)base + (int)rank[e]] = ei[e];
}

// ---------- aggregate 1: XCD-bound panel SpMM ----------
// 1-D grid, panel = wgid & 3 (4 panels x 32 features); wave per node.
// lane = es*4+fl: es = edge slot (16 edges in flight), fl = feature quad.
// Each lane gathers 16B (8 bf16) of its edge's 64B panel slice; per-XCD
// footprint = 3.2 MB panel -> L2-resident under round-robin wg->XCD dispatch.
__global__ __launch_bounds__(256) void agg1_kernel(
    const int* __restrict__ row_ptr, const int* __restrict__ csr,
    const float* __restrict__ inorm, const unsigned short* __restrict__ featb,
    unsigned short* __restrict__ aggF) {
  int wgid = blockIdx.x;
  int panel = wgid & 3;
  int node = ((wgid >> 2) << 2) + (threadIdx.x >> 6);
  if (node >= NNODES) return;
  int lane = threadIdx.x & 63;
  int es = lane >> 2;
  int fl = lane & 3;
  const unsigned short* tab = featb + panel * 32 + fl * 8;
  int beg = row_ptr[node], end = row_ptr[node + 1];
  float a0 = 0.f, a1 = 0.f, a2 = 0.f, a3 = 0.f, a4 = 0.f, a5 = 0.f, a6 = 0.f, a7 = 0.f;
  for (int e = beg + es; e < end; e += 16) {
    int s = csr[e];
    uint4 v = *(const uint4*)(tab + (size_t)s * FIN);
    a0 += bf_lo(v.x); a1 += bf_hi(v.x); a2 += bf_lo(v.y); a3 += bf_hi(v.y);
    a4 += bf_lo(v.z); a5 += bf_hi(v.z); a6 += bf_lo(v.w); a7 += bf_hi(v.w);
  }
  // reduce over the 16 edge slots (lane strides 4,8,16,32)
#pragma unroll
  for (int d = 4; d <= 32; d <<= 1) {
    a0 += __shfl_xor(a0, d, 64); a1 += __shfl_xor(a1, d, 64);
    a2 += __shfl_xor(a2, d, 64); a3 += __shfl_xor(a3, d, 64);
    a4 += __shfl_xor(a4, d, 64); a5 += __shfl_xor(a5, d, 64);
    a6 += __shfl_xor(a6, d, 64); a7 += __shfl_xor(a7, d, 64);
  }
  if (es == 0) {
    float inn = inorm[node];
    uint4 pk;
    pk.x = (unsigned)f2bf(a0 * inn) | ((unsigned)f2bf(a1 * inn) << 16);
    pk.y = (unsigned)f2bf(a2 * inn) | ((unsigned)f2bf(a3 * inn) << 16);
    pk.z = (unsigned)f2bf(a4 * inn) | ((unsigned)f2bf(a5 * inn) << 16);
    pk.w = (unsigned)f2bf(a6 * inn) | ((unsigned)f2bf(a7 * inn) << 16);
    *(uint4*)(aggF + (size_t)node * FIN + panel * 32 + fl * 8) = pk;
  }
}

// ---------- aggregate 2: XCD-bound panel SpMM, +b2, f32 out ----------
// 1-D grid, panel = wgid & 7 (8 panels x 32 features); per-XCD footprint =
// 3.2 MB panel of the 25.6 MB h2s table -> L2-resident per XCD.
__global__ __launch_bounds__(256) void agg2_kernel(
    const int* __restrict__ row_ptr, const int* __restrict__ csr,
    const float* __restrict__ inorm, const unsigned short* __restrict__ h2s,
    const float* __restrict__ b2, float* __restrict__ out) {
  int wgid = blockIdx.x;
  int panel = wgid & 7;
  int node = ((wgid >> 3) << 2) + (threadIdx.x >> 6);
  if (node >= NNODES) return;
  int lane = threadIdx.x & 63;
  int es = lane >> 2;
  int fl = lane & 3;
  const unsigned short* tab = h2s + panel * 32 + fl * 8;
  int beg = row_ptr[node], end = row_ptr[node + 1];
  float a0 = 0.f, a1 = 0.f, a2 = 0.f, a3 = 0.f, a4 = 0.f, a5 = 0.f, a6 = 0.f, a7 = 0.f;
  for (int e = beg + es; e < end; e += 16) {
    int s = csr[e];
    uint4 v = *(const uint4*)(tab + (size_t)s * FOUT);
    a0 += bf_lo(v.x); a1 += bf_hi(v.x); a2 += bf_lo(v.y); a3 += bf_hi(v.y);
    a4 += bf_lo(v.z); a5 += bf_hi(v.z); a6 += bf_lo(v.w); a7 += bf_hi(v.w);
  }
#pragma unroll
  for (int d = 4; d <= 32; d <<= 1) {
    a0 += __shfl_xor(a0, d, 64); a1 += __shfl_xor(a1, d, 64);
    a2 += __shfl_xor(a2, d, 64); a3 += __shfl_xor(a3, d, 64);
    a4 += __shfl_xor(a4, d, 64); a5 += __shfl_xor(a5, d, 64);
    a6 += __shfl_xor(a6, d, 64); a7 += __shfl_xor(a7, d, 64);
  }
  if (es == 0) {
    int f = panel * 32 + fl * 8;
    float inn = inorm[node];
    float4 b0 = *(const float4*)(b2 + f);
    float4 b1 = *(const float4*)(b2 + f + 4);
    float4 r0, r1;
    r0.x = fmaf(a0, inn, b0.x); r0.y = fmaf(a1, inn, b0.y);
    r0.z = fmaf(a2, inn, b0.z); r0.w = fmaf(a3, inn, b0.w);
    r1.x = fmaf(a4, inn, b1.x); r1.y = fmaf(a5, inn, b1.y);
    r1.z = fmaf(a6, inn, b1.z); r1.w = fmaf(a7, inn, b1.w);
    float* op = out + (size_t)node * FOUT + f;
    *(float4*)op = r0;
    *(float4*)(op + 4) = r1;
  }
}

// ---------- GEMM: C[M][N](bf16) = A[M][K] @ Bt[N][K]^T, opt bias+relu, opt row-scale ----------
__device__ __forceinline__ f32x4 mfma16(bf16x8 a, bf16x8 b, f32x4 c) {
  return __builtin_amdgcn_mfma_f32_16x16x32_bf16(a, b, c, 0, 0, 0);
}

__global__ __launch_bounds__(256) void gemm_bf16(
    const __bf16* __restrict__ A, const __bf16* __restrict__ Bt,
    const float* __restrict__ bias, const float* __restrict__ row_scale,
    __bf16* __restrict__ C, int M, int N, int K, int relu) {
  __shared__ __attribute__((aligned(16))) __bf16 As[128 * 64];
  __shared__ __attribute__((aligned(16))) __bf16 Bs[128 * 64];
  const int tid = threadIdx.x;
  const int lane = tid & 63;
  const int wave = tid >> 6;
  const int wm = (wave >> 1) << 6;
  const int wn = (wave & 1) << 6;
  const int r16 = lane & 15;
  const int kg = lane >> 4;
  const int m0 = blockIdx.x * 128;
  const int n0 = blockIdx.y * 128;
  f32x4 acc[4][4];
#pragma unroll
  for (int m = 0; m < 4; ++m)
#pragma unroll
    for (int n = 0; n < 4; ++n) acc[m][n] = f32x4{0.f, 0.f, 0.f, 0.f};

  for (int k0 = 0; k0 < K; k0 += 64) {
    __syncthreads();
#pragma unroll
    for (int i = 0; i < 4; ++i) {
      int c = tid + (i << 8);      // chunk 0..1023
      int row = c >> 3;            // 0..127
      int col = c & 7;             // 16B chunk in row
      int sw = ((col ^ (row & 7)) << 3);
      int ga = m0 + row;
      uint4 av = make_uint4(0u, 0u, 0u, 0u);
      if (ga < M) av = *(const uint4*)(A + (size_t)ga * K + k0 + (col << 3));
      *(uint4*)(As + row * 64 + sw) = av;
      uint4 bv = *(const uint4*)(Bt + (size_t)(n0 + row) * K + k0 + (col << 3));
      *(uint4*)(Bs + row * 64 + sw) = bv;
    }
    __syncthreads();
#pragma unroll
    for (int kk = 0; kk < 2; ++kk) {
      int kc = (kk << 2) + kg;   // logical 16B chunk 0..7
      bf16x8 a[4], b[4];
#pragma unroll
      for (int m = 0; m < 4; ++m) {
        int r = wm + (m << 4) + r16;
        a[m] = *(const bf16x8*)(As + r * 64 + ((kc ^ (r & 7)) << 3));
      }
#pragma unroll
      for (int n = 0; n < 4; ++n) {
        int r = wn + (n << 4) + r16;
        b[n] = *(const bf16x8*)(Bs + r * 64 + ((kc ^ (r & 7)) << 3));
      }
#pragma unroll
      for (int m = 0; m < 4; ++m)
#pragma unroll
        for (int n = 0; n < 4; ++n)
          acc[m][n] = mfma16(a[m], b[n], acc[m][n]);
    }
  }
  // epilogue: C row = m0+wm+m*16+kg*4+j, col = n0+wn+n*16+r16
#pragma unroll
  for (int m = 0; m < 4; ++m) {
#pragma unroll
    for (int j = 0; j < 4; ++j) {
      int row = m0 + wm + (m << 4) + (kg << 2) + j;
      if (row < M) {
        float sc = row_scale ? row_scale[row] : 1.f;
#pragma unroll
        for (int n = 0; n < 4; ++n) {
          int col = n0 + wn + (n << 4) + r16;
          float v = acc[m][n][j] + (bias ? bias[col] : 0.f);
          if (relu) v = fmaxf(v, 0.f);
          v *= sc;
          unsigned short h = f2bf(v);
          C[(size_t)row * N + col] = *(__bf16*)&h;
        }
      }
    }
  }
}

extern "C" void kernel_launch(void* const* d_in, const int* in_sizes, int n_in,
                              void* d_out, int out_size, void* d_ws, size_t ws_size,
                              hipStream_t stream) {
  const float* features = (const float*)d_in[0];
  const float* W1 = (const float*)d_in[1];
  const float* b1 = (const float*)d_in[2];
  const float* W2 = (const float*)d_in[3];
  const float* b2 = (const float*)d_in[4];
  const int* ei = (const int*)d_in[5];
  float* out = (float*)d_out;

  char* ws = (char*)d_ws;
  size_t off = 0;
  auto alloc = [&](size_t bytes) -> void* {
    void* p = ws + off;
    off += (bytes + 255) & ~(size_t)255;
    return p;
  };
  float* onorm  = (float*)alloc((size_t)NNODES * 4);
  float* inorm  = (float*)alloc((size_t)NNODES * 4);
  int* din      = (int*)alloc((size_t)NNODES * 4);
  int* row_ptr  = (int*)alloc((size_t)(NNODES + 1) * 4);
  int* csr_src  = (int*)alloc((size_t)NEDGES * 4);
  int* blocksums = (int*)alloc((size_t)SCAN_NB * 4);
  int* blockoffs = (int*)alloc((size_t)SCAN_NB * 4);
  unsigned short* featb = (unsigned short*)alloc((size_t)NNODES * FIN * 2);
  unsigned short* aggF  = (unsigned short*)alloc((size_t)NNODES * FIN * 2);
  __bf16* h1  = (__bf16*)alloc((size_t)NNODES * FHID * 2);   // 38.4 MB
  __bf16* h2s = (__bf16*)alloc((size_t)NNODES * FOUT * 2);
  __bf16* W1t = (__bf16*)alloc((size_t)FIN * FHID * 2);
  __bf16* W2t = (__bf16*)alloc((size_t)FHID * FOUT * 2);
  (void)ws_size; (void)n_in; (void)in_sizes; (void)out_size;

  // hist scratch aliases h1 (dead until gemm1, which runs after fill):
  // psrc 6.4 MB | pdst 6.4 MB | rank 1.6 MB  (total 14.4 MB < 38.4 MB)
  unsigned* psrc = (unsigned*)h1;
  unsigned* pdst = psrc + (size_t)HB * HW;
  unsigned short* rank = (unsigned short*)(pdst + (size_t)HB * HW);

  // graph preprocessing: LDS histograms (no global atomics), fused norms,
  // exclusive scan, rank-based atomic-free CSR fill
  hist_kernel<<<dim3(HB, 2), 256, 0, stream>>>(ei, psrc, pdst, rank);
  reduce_hist<<<(HW + 255) / 256, 256, 0, stream>>>(psrc, pdst, din, onorm, inorm);
  scan_part1<<<SCAN_NB, 256, 0, stream>>>(din, blocksums);
  scan_mid<<<1, 64, 0, stream>>>(blocksums, blockoffs);
  scan_part2<<<SCAN_NB, 256, 0, stream>>>(din, blockoffs, row_ptr);
  fill_kernel<<<(NEDGES + 255) / 256, 256, 0, stream>>>(ei, rank, pdst, row_ptr, csr_src);

  // converts (featb = onorm-prescaled bf16 features)
  cvt_feat_kernel<<<(NNODES * FIN / 4 + 255) / 256, 256, 0, stream>>>(
      features, onorm, featb, NNODES * FIN / 4);
  wt_kernel<<<(FIN * FHID + 255) / 256, 256, 0, stream>>>(W1, W1t, FIN, FHID);
  wt_kernel<<<(FHID * FOUT + 255) / 256, 256, 0, stream>>>(W2, W2t, FHID, FOUT);

  // conv1: aggregate (XCD-bound panels) then transform (+bias, relu)
  agg1_kernel<<<((NNODES + 3) / 4) * 4, 256, 0, stream>>>(
      row_ptr, csr_src, inorm, featb, aggF);
  gemm_bf16<<<dim3((NNODES + 127) / 128, FHID / 128), 256, 0, stream>>>(
      (const __bf16*)aggF, W1t, b1, nullptr, h1, NNODES, FHID, FIN, 1);

  // conv2: transform (epilogue prescales rows by onorm) then aggregate (+b2)
  gemm_bf16<<<dim3((NNODES + 127) / 128, FOUT / 128), 256, 0, stream>>>(
      h1, W2t, nullptr, onorm, h2s, NNODES, FOUT, FHID, 0);
  agg2_kernel<<<((NNODES + 3) / 4) * 8, 256, 0, stream>>>(
      row_ptr, csr_src, inorm, (const unsigned short*)h2s, b2, out);
}

// Round 11
// 310.291 us; speedup vs baseline: 1.4000x; 1.4000x over previous
//
#include <hip/hip_runtime.h>
#include <hip/hip_bf16.h>

typedef float f32x4 __attribute__((ext_vector_type(4)));
typedef __bf16 bf16x8 __attribute__((ext_vector_type(8)));

#define NNODES 50000
#define NEDGES 800000
#define FIN 128
#define FHID 384
#define FOUT 256

// scan geometry: 49 blocks x 256 threads x 4 elements
#define SCAN_NB ((NNODES + 1023) / 1024)

// histogram geometry: 128 blocks x 1024 threads, packed 2xu16 counts in LDS
#define HB 128
#define EPB (NEDGES / HB)   // 6250 edges per hist block
#define HW (NNODES / 2)     // 25000 u32 words (2 nodes/word)

__device__ __forceinline__ float bf_lo(unsigned u) { return __uint_as_float(u << 16); }
__device__ __forceinline__ float bf_hi(unsigned u) { return __uint_as_float(u & 0xffff0000u); }
__device__ __forceinline__ unsigned short f2bf(float f) {
  unsigned u = __float_as_uint(f);
  u += 0x7fffu + ((u >> 16) & 1u);
  return (unsigned short)(u >> 16);
}

// ---------- feature f32 -> bf16, prescaled by out_norm[row] ----------
__global__ void cvt_feat_kernel(const float* __restrict__ f,
                                const float* __restrict__ onorm,
                                unsigned short* __restrict__ o, int n4) {
  int i = blockIdx.x * blockDim.x + threadIdx.x;
  if (i >= n4) return;
  float4 v = *(const float4*)(f + (size_t)i * 4);
  float w = onorm[(i * 4) >> 7];  // row = (i*4)/FIN
  ushort4 r;
  r.x = f2bf(v.x * w); r.y = f2bf(v.y * w);
  r.z = f2bf(v.z * w); r.w = f2bf(v.w * w);
  *(ushort4*)(o + (size_t)i * 4) = r;
}

// ---------- W1 and W2 f32 -> transposed bf16, fused in one launch ----------
__global__ void wt_both(const float* __restrict__ W1, const float* __restrict__ W2,
                        __bf16* __restrict__ W1t, __bf16* __restrict__ W2t) {
  int i = blockIdx.x * blockDim.x + threadIdx.x;
  if (i < FIN * FHID) {
    int k = i / FHID, n = i % FHID;
    unsigned short b = f2bf(W1[i]);
    W1t[(size_t)n * FIN + k] = *(__bf16*)&b;
  } else if (i < FIN * FHID + FHID * FOUT) {
    int j = i - FIN * FHID;
    int k = j / FOUT, n = j % FOUT;
    unsigned short b = f2bf(W2[j]);
    W2t[(size_t)n * FHID + k] = *(__bf16*)&b;
  }
}

// ---------- LDS histogram of node occurrences (no global atomics) ----------
// grid (HB, 2): y=0 counts src -> psrc partials; y=1 counts dst -> pdst partials + per-edge rank
__global__ __launch_bounds__(1024) void hist_kernel(
    const int* __restrict__ ei, unsigned* __restrict__ psrc,
    unsigned* __restrict__ pdst, unsigned short* __restrict__ rank) {
  __shared__ unsigned hist[HW];
  int b = blockIdx.x, pass = blockIdx.y, t = threadIdx.x;
  for (int i = t; i < HW; i += 1024) hist[i] = 0;
  __syncthreads();
  const int* idx = ei + (pass ? NEDGES : 0) + b * EPB;
  if (pass == 0) {
    for (int i = t; i < EPB; i += 1024) {
      int n = idx[i];
      atomicAdd(&hist[n >> 1], 1u << ((n & 1) << 4));
    }
  } else {
    for (int i = t; i < EPB; i += 1024) {
      int n = idx[i];
      unsigned sh = (n & 1) << 4;
      unsigned old = atomicAdd(&hist[n >> 1], 1u << sh);
      rank[b * EPB + i] = (unsigned short)((old >> sh) & 0xFFFFu);
    }
  }
  __syncthreads();
  unsigned* dst = (pass ? pdst : psrc) + (size_t)b * HW;
  for (int i = t; i < HW; i += 1024) dst[i] = hist[i];
}

// ---------- reduce partials -> degrees + norms; convert pdst to per-block exclusive prefixes ----------
__global__ __launch_bounds__(256) void reduce_hist(
    const unsigned* __restrict__ psrc, unsigned* __restrict__ pdst,
    int* __restrict__ din, float* __restrict__ onorm, float* __restrict__ inorm) {
  int w = blockIdx.x * blockDim.x + threadIdx.x;
  if (w >= HW) return;
  unsigned sl = 0, sh = 0;
#pragma unroll 8
  for (int b = 0; b < HB; ++b) {
    unsigned v = psrc[(size_t)b * HW + w];
    sl += v & 0xFFFFu; sh += v >> 16;
  }
  unsigned rl = 0, rh = 0;
#pragma unroll 8
  for (int b = 0; b < HB; ++b) {
    size_t o = (size_t)b * HW + w;
    unsigned v = pdst[o];
    pdst[o] = rl | (rh << 16);  // exclusive prefix over blocks, packed 2xu16
    rl += v & 0xFFFFu; rh += v >> 16;
  }
  int n0 = 2 * w, n1 = 2 * w + 1;
  din[n0] = (int)rl; din[n1] = (int)rh;
  onorm[n0] = rsqrtf((float)(sl ? sl : 1u));
  onorm[n1] = rsqrtf((float)(sh ? sh : 1u));
  inorm[n0] = rsqrtf((float)(rl ? rl : 1u));
  inorm[n1] = rsqrtf((float)(rh ? rh : 1u));
}

// ---------- multi-block exclusive scan, stage 1: per-block sums ----------
__global__ __launch_bounds__(256) void scan_part1(const int* __restrict__ deg,
                                                  int* __restrict__ blocksums) {
  int b = blockIdx.x, t = threadIdx.x;
  int base = b * 1024 + t * 4;
  int s = 0;
  if (base + 4 <= NNODES) {
    int4 v = *(const int4*)(deg + base);
    s = v.x + v.y + v.z + v.w;
  } else {
    for (int j = 0; j < 4; ++j)
      if (base + j < NNODES) s += deg[base + j];
  }
  for (int d = 32; d >= 1; d >>= 1) s += __shfl_down(s, d, 64);
  __shared__ int ws[4];
  int lane = t & 63, w = t >> 6;
  if (lane == 0) ws[w] = s;
  __syncthreads();
  if (t == 0) blocksums[b] = ws[0] + ws[1] + ws[2] + ws[3];
}

// ---------- stage 2: one wave scans the block sums (SCAN_NB <= 64) ----------
__global__ void scan_mid(const int* __restrict__ bs, int* __restrict__ boff) {
  int t = threadIdx.x;  // 64 threads
  int v = (t < SCAN_NB) ? bs[t] : 0;
  int x = v;
  for (int d = 1; d < 64; d <<= 1) {
    int y = __shfl_up(x, d, 64);
    if (t >= d) x += y;
  }
  if (t < SCAN_NB) boff[t] = x - v;  // exclusive
}

// ---------- stage 3: intra-block exclusive scan + write row_ptr ----------
__global__ __launch_bounds__(256) void scan_part2(const int* __restrict__ deg,
                                                  const int* __restrict__ boff,
                                                  int* __restrict__ row_ptr) {
  int b = blockIdx.x, t = threadIdx.x;
  int base = b * 1024 + t * 4;
  int v0 = 0, v1 = 0, v2 = 0, v3 = 0;
  if (base + 4 <= NNODES) {
    int4 v = *(const int4*)(deg + base);
    v0 = v.x; v1 = v.y; v2 = v.z; v3 = v.w;
  } else {
    if (base + 0 < NNODES) v0 = deg[base + 0];
    if (base + 1 < NNODES) v1 = deg[base + 1];
    if (base + 2 < NNODES) v2 = deg[base + 2];
    if (base + 3 < NNODES) v3 = deg[base + 3];
  }
  int s = v0 + v1 + v2 + v3;
  int x = s;
  int lane = t & 63, w = t >> 6;
  for (int d = 1; d < 64; d <<= 1) {
    int y = __shfl_up(x, d, 64);
    if (lane >= d) x += y;
  }
  __shared__ int ws[4];
  if (lane == 63) ws[w] = x;
  __syncthreads();
  int woff = 0;
  for (int i = 0; i < w; ++i) woff += ws[i];
  int off = boff[b] + woff + (x - s);  // exclusive prefix for this thread
  if (base + 0 < NNODES) { row_ptr[base + 0] = off; off += v0; }
  if (base + 1 < NNODES) { row_ptr[base + 1] = off; off += v1; }
  if (base + 2 < NNODES) { row_ptr[base + 2] = off; off += v2; }
  if (base + 3 < NNODES) { row_ptr[base + 3] = off; off += v3; }
  if (base < NNODES && base + 4 >= NNODES) row_ptr[NNODES] = off;
}

// ---------- CSR fill, atomic-free: pos = row_ptr[dst] + prefix[b][dst] + rank[e] ----------
__global__ void fill_kernel(const int* __restrict__ ei,
                            const unsigned short* __restrict__ rank,
                            const unsigned* __restrict__ pdst,
                            const int* __restrict__ row_ptr,
                            int* __restrict__ csr) {
  int e = blockIdx.x * blockDim.x + threadIdx.x;
  if (e >= NEDGES) return;
  int n = ei[NEDGES + e];
  int b = e / EPB;  // which hist block counted this edge
  unsigned base = (pdst[(size_t)b * HW + (n >> 1)] >> ((n & 1) << 4)) & 0xFFFFu;
  csr[row_ptr[n] + (int)base + (int)rank[e]] = ei[e];
}

// ---------- aggregate 1: one wave per node, 4 lane-groups of 16, 16B/lane gathers ----------
// featb prescaled by out_norm. lane = quarter*16 + fl; lane covers features [fl*8, fl*8+8)
// 4 gathers in flight per lane in the main loop (16 edges per wave-iteration).
__global__ __launch_bounds__(256) void agg1_kernel(
    const int* __restrict__ row_ptr, const int* __restrict__ csr,
    const float* __restrict__ inorm, const unsigned short* __restrict__ featb,
    unsigned short* __restrict__ aggF) {
  int node = (blockIdx.x << 2) + (threadIdx.x >> 6);
  if (node >= NNODES) return;
  int lane = threadIdx.x & 63;
  int quarter = lane >> 4;
  int fl8 = (lane & 15) << 3;
  const unsigned short* tab = featb + fl8;
  int beg = row_ptr[node], end = row_ptr[node + 1];
  float a0 = 0.f, a1 = 0.f, a2 = 0.f, a3 = 0.f, a4 = 0.f, a5 = 0.f, a6 = 0.f, a7 = 0.f;
  int e = beg;
  for (; e + 16 <= end; e += 16) {
    int s0 = __builtin_nontemporal_load(&csr[e + quarter]);
    int s1 = __builtin_nontemporal_load(&csr[e + 4 + quarter]);
    int s2 = __builtin_nontemporal_load(&csr[e + 8 + quarter]);
    int s3 = __builtin_nontemporal_load(&csr[e + 12 + quarter]);
    uint4 v0 = *(const uint4*)(tab + (size_t)s0 * FIN);
    uint4 v1 = *(const uint4*)(tab + (size_t)s1 * FIN);
    uint4 v2 = *(const uint4*)(tab + (size_t)s2 * FIN);
    uint4 v3 = *(const uint4*)(tab + (size_t)s3 * FIN);
    a0 += bf_lo(v0.x); a1 += bf_hi(v0.x); a2 += bf_lo(v0.y); a3 += bf_hi(v0.y);
    a4 += bf_lo(v0.z); a5 += bf_hi(v0.z); a6 += bf_lo(v0.w); a7 += bf_hi(v0.w);
    a0 += bf_lo(v1.x); a1 += bf_hi(v1.x); a2 += bf_lo(v1.y); a3 += bf_hi(v1.y);
    a4 += bf_lo(v1.z); a5 += bf_hi(v1.z); a6 += bf_lo(v1.w); a7 += bf_hi(v1.w);
    a0 += bf_lo(v2.x); a1 += bf_hi(v2.x); a2 += bf_lo(v2.y); a3 += bf_hi(v2.y);
    a4 += bf_lo(v2.z); a5 += bf_hi(v2.z); a6 += bf_lo(v2.w); a7 += bf_hi(v2.w);
    a0 += bf_lo(v3.x); a1 += bf_hi(v3.x); a2 += bf_lo(v3.y); a3 += bf_hi(v3.y);
    a4 += bf_lo(v3.z); a5 += bf_hi(v3.z); a6 += bf_lo(v3.w); a7 += bf_hi(v3.w);
  }
  if (e + 8 <= end) {
    int s0 = __builtin_nontemporal_load(&csr[e + quarter]);
    int s1 = __builtin_nontemporal_load(&csr[e + 4 + quarter]);
    uint4 v0 = *(const uint4*)(tab + (size_t)s0 * FIN);
    uint4 v1 = *(const uint4*)(tab + (size_t)s1 * FIN);
    a0 += bf_lo(v0.x); a1 += bf_hi(v0.x); a2 += bf_lo(v0.y); a3 += bf_hi(v0.y);
    a4 += bf_lo(v0.z); a5 += bf_hi(v0.z); a6 += bf_lo(v0.w); a7 += bf_hi(v0.w);
    a0 += bf_lo(v1.x); a1 += bf_hi(v1.x); a2 += bf_lo(v1.y); a3 += bf_hi(v1.y);
    a4 += bf_lo(v1.z); a5 += bf_hi(v1.z); a6 += bf_lo(v1.w); a7 += bf_hi(v1.w);
    e += 8;
  }
  for (int t = e + quarter; t < end; t += 4) {
    int s0 = __builtin_nontemporal_load(&csr[t]);
    uint4 v0 = *(const uint4*)(tab + (size_t)s0 * FIN);
    a0 += bf_lo(v0.x); a1 += bf_hi(v0.x); a2 += bf_lo(v0.y); a3 += bf_hi(v0.y);
    a4 += bf_lo(v0.z); a5 += bf_hi(v0.z); a6 += bf_lo(v0.w); a7 += bf_hi(v0.w);
  }
  // combine the 4 lane-groups (lanes fl, fl+16, fl+32, fl+48)
  a0 += __shfl_xor(a0, 16, 64); a1 += __shfl_xor(a1, 16, 64);
  a2 += __shfl_xor(a2, 16, 64); a3 += __shfl_xor(a3, 16, 64);
  a4 += __shfl_xor(a4, 16, 64); a5 += __shfl_xor(a5, 16, 64);
  a6 += __shfl_xor(a6, 16, 64); a7 += __shfl_xor(a7, 16, 64);
  a0 += __shfl_xor(a0, 32, 64); a1 += __shfl_xor(a1, 32, 64);
  a2 += __shfl_xor(a2, 32, 64); a3 += __shfl_xor(a3, 32, 64);
  a4 += __shfl_xor(a4, 32, 64); a5 += __shfl_xor(a5, 32, 64);
  a6 += __shfl_xor(a6, 32, 64); a7 += __shfl_xor(a7, 32, 64);
  // each of the 4 lanes sharing fl writes a distinct pair of the 8 features
  float p0 = (quarter == 0) ? a0 : (quarter == 1) ? a2 : (quarter == 2) ? a4 : a6;
  float p1 = (quarter == 0) ? a1 : (quarter == 1) ? a3 : (quarter == 2) ? a5 : a7;
  float inn = inorm[node];
  unsigned pk = (unsigned)f2bf(p0 * inn) | ((unsigned)f2bf(p1 * inn) << 16);
  *(unsigned*)(aggF + (size_t)node * FIN + fl8 + (quarter << 1)) = pk;
}

// ---------- aggregate 2: one wave per node, 2 lane-halves, 16B/lane gathers, +b2, f32 out ----------
// h2s prescaled by out_norm. lane = half*32 + fl; lane covers features [fl*8, fl*8+8)
// 4 gathers in flight per lane in the main loop (8 edges per wave-iteration).
__global__ __launch_bounds__(256) void agg2_kernel(
    const int* __restrict__ row_ptr, const int* __restrict__ csr,
    const float* __restrict__ inorm, const unsigned short* __restrict__ h2s,
    const float* __restrict__ b2, float* __restrict__ out) {
  int node = (blockIdx.x << 2) + (threadIdx.x >> 6);
  if (node >= NNODES) return;
  int lane = threadIdx.x & 63;
  int half = lane >> 5;
  int fl8 = (lane & 31) << 3;
  const unsigned short* tab = h2s + fl8;
  int beg = row_ptr[node], end = row_ptr[node + 1];
  float a0 = 0.f, a1 = 0.f, a2 = 0.f, a3 = 0.f, a4 = 0.f, a5 = 0.f, a6 = 0.f, a7 = 0.f;
  int e = beg;
  for (; e + 8 <= end; e += 8) {
    int s0 = __builtin_nontemporal_load(&csr[e + half]);
    int s1 = __builtin_nontemporal_load(&csr[e + 2 + half]);
    int s2 = __builtin_nontemporal_load(&csr[e + 4 + half]);
    int s3 = __builtin_nontemporal_load(&csr[e + 6 + half]);
    uint4 v0 = *(const uint4*)(tab + (size_t)s0 * FOUT);
    uint4 v1 = *(const uint4*)(tab + (size_t)s1 * FOUT);
    uint4 v2 = *(const uint4*)(tab + (size_t)s2 * FOUT);
    uint4 v3 = *(const uint4*)(tab + (size_t)s3 * FOUT);
    a0 += bf_lo(v0.x); a1 += bf_hi(v0.x); a2 += bf_lo(v0.y); a3 += bf_hi(v0.y);
    a4 += bf_lo(v0.z); a5 += bf_hi(v0.z); a6 += bf_lo(v0.w); a7 += bf_hi(v0.w);
    a0 += bf_lo(v1.x); a1 += bf_hi(v1.x); a2 += bf_lo(v1.y); a3 += bf_hi(v1.y);
    a4 += bf_lo(v1.z); a5 += bf_hi(v1.z); a6 += bf_lo(v1.w); a7 += bf_hi(v1.w);
    a0 += bf_lo(v2.x); a1 += bf_hi(v2.x); a2 += bf_lo(v2.y); a3 += bf_hi(v2.y);
    a4 += bf_lo(v2.z); a5 += bf_hi(v2.z); a6 += bf_lo(v2.w); a7 += bf_hi(v2.w);
    a0 += bf_lo(v3.x); a1 += bf_hi(v3.x); a2 += bf_lo(v3.y); a3 += bf_hi(v3.y);
    a4 += bf_lo(v3.z); a5 += bf_hi(v3.z); a6 += bf_lo(v3.w); a7 += bf_hi(v3.w);
  }
  if (e + 4 <= end) {
    int s0 = __builtin_nontemporal_load(&csr[e + half]);
    int s1 = __builtin_nontemporal_load(&csr[e + 2 + half]);
    uint4 v0 = *(const uint4*)(tab + (size_t)s0 * FOUT);
    uint4 v1 = *(const uint4*)(tab + (size_t)s1 * FOUT);
    a0 += bf_lo(v0.x); a1 += bf_hi(v0.x); a2 += bf_lo(v0.y); a3 += bf_hi(v0.y);
    a4 += bf_lo(v0.z); a5 += bf_hi(v0.z); a6 += bf_lo(v0.w); a7 += bf_hi(v0.w);
    a0 += bf_lo(v1.x); a1 += bf_hi(v1.x); a2 += bf_lo(v1.y); a3 += bf_hi(v1.y);
    a4 += bf_lo(v1.z); a5 += bf_hi(v1.z); a6 += bf_lo(v1.w); a7 += bf_hi(v1.w);
    e += 4;
  }
  for (int t = e + half; t < end; t += 2) {
    int s0 = __builtin_nontemporal_load(&csr[t]);
    uint4 v0 = *(const uint4*)(tab + (size_t)s0 * FOUT);
    a0 += bf_lo(v0.x); a1 += bf_hi(v0.x); a2 += bf_lo(v0.y); a3 += bf_hi(v0.y);
    a4 += bf_lo(v0.z); a5 += bf_hi(v0.z); a6 += bf_lo(v0.w); a7 += bf_hi(v0.w);
  }
  // combine the 2 lane-halves (lanes fl, fl+32)
  a0 += __shfl_xor(a0, 32, 64); a1 += __shfl_xor(a1, 32, 64);
  a2 += __shfl_xor(a2, 32, 64); a3 += __shfl_xor(a3, 32, 64);
  a4 += __shfl_xor(a4, 32, 64); a5 += __shfl_xor(a5, 32, 64);
  a6 += __shfl_xor(a6, 32, 64); a7 += __shfl_xor(a7, 32, 64);
  // half 0 writes features fl8..fl8+4, half 1 writes fl8+4..fl8+8
  float q0 = half ? a4 : a0;
  float q1 = half ? a5 : a1;
  float q2 = half ? a6 : a2;
  float q3 = half ? a7 : a3;
  int f = fl8 + (half << 2);
  float inn = inorm[node];
  float4 bv = *(const float4*)(b2 + f);
  f32x4 r;
  r.x = fmaf(q0, inn, bv.x);
  r.y = fmaf(q1, inn, bv.y);
  r.z = fmaf(q2, inn, bv.z);
  r.w = fmaf(q3, inn, bv.w);
  // final output, never re-read: nt store keeps L2 for the gather table
  // (clang vector type f32x4, not HIP_vector_type, for the builtin)
  __builtin_nontemporal_store(r, (f32x4*)(out + (size_t)node * FOUT + f));
}

// ---------- GEMM: C[M][N](bf16) = A[M][K] @ Bt[N][K]^T, opt bias+relu, opt row-scale ----------
__device__ __forceinline__ f32x4 mfma16(bf16x8 a, bf16x8 b, f32x4 c) {
  return __builtin_amdgcn_mfma_f32_16x16x32_bf16(a, b, c, 0, 0, 0);
}

__global__ __launch_bounds__(256) void gemm_bf16(
    const __bf16* __restrict__ A, const __bf16* __restrict__ Bt,
    const float* __restrict__ bias, const float* __restrict__ row_scale,
    __bf16* __restrict__ C, int M, int N, int K, int relu) {
  __shared__ __attribute__((aligned(16))) __bf16 As[128 * 64];
  __shared__ __attribute__((aligned(16))) __bf16 Bs[128 * 64];
  const int tid = threadIdx.x;
  const int lane = tid & 63;
  const int wave = tid >> 6;
  const int wm = (wave >> 1) << 6;
  const int wn = (wave & 1) << 6;
  const int r16 = lane & 15;
  const int kg = lane >> 4;
  const int m0 = blockIdx.x * 128;
  const int n0 = blockIdx.y * 128;
  f32x4 acc[4][4];
#pragma unroll
  for (int m = 0; m < 4; ++m)
#pragma unroll
    for (int n = 0; n < 4; ++n) acc[m][n] = f32x4{0.f, 0.f, 0.f, 0.f};

  for (int k0 = 0; k0 < K; k0 += 64) {
    __syncthreads();
#pragma unroll
    for (int i = 0; i < 4; ++i) {
      int c = tid + (i << 8);      // chunk 0..1023
      int row = c >> 3;            // 0..127
      int col = c & 7;             // 16B chunk in row
      int sw = ((col ^ (row & 7)) << 3);
      int ga = m0 + row;
      uint4 av = make_uint4(0u, 0u, 0u, 0u);
      if (ga < M) av = *(const uint4*)(A + (size_t)ga * K + k0 + (col << 3));
      *(uint4*)(As + row * 64 + sw) = av;
      uint4 bv = *(const uint4*)(Bt + (size_t)(n0 + row) * K + k0 + (col << 3));
      *(uint4*)(Bs + row * 64 + sw) = bv;
    }
    __syncthreads();
#pragma unroll
    for (int kk = 0; kk < 2; ++kk) {
      int kc = (kk << 2) + kg;   // logical 16B chunk 0..7
      bf16x8 a[4], b[4];
#pragma unroll
      for (int m = 0; m < 4; ++m) {
        int r = wm + (m << 4) + r16;
        a[m] = *(const bf16x8*)(As + r * 64 + ((kc ^ (r & 7)) << 3));
      }
#pragma unroll
      for (int n = 0; n < 4; ++n) {
        int r = wn + (n << 4) + r16;
        b[n] = *(const bf16x8*)(Bs + r * 64 + ((kc ^ (r & 7)) << 3));
      }
#pragma unroll
      for (int m = 0; m < 4; ++m)
#pragma unroll
        for (int n = 0; n < 4; ++n)
          acc[m][n] = mfma16(a[m], b[n], acc[m][n]);
    }
  }
  // epilogue: C row = m0+wm+m*16+kg*4+j, col = n0+wn+n*16+r16
#pragma unroll
  for (int m = 0; m < 4; ++m) {
#pragma unroll
    for (int j = 0; j < 4; ++j) {
      int row = m0 + wm + (m << 4) + (kg << 2) + j;
      if (row < M) {
        float sc = row_scale ? row_scale[row] : 1.f;
#pragma unroll
        for (int n = 0; n < 4; ++n) {
          int col = n0 + wn + (n << 4) + r16;
          float v = acc[m][n][j] + (bias ? bias[col] : 0.f);
          if (relu) v = fmaxf(v, 0.f);
          v *= sc;
          unsigned short h = f2bf(v);
          C[(size_t)row * N + col] = *(__bf16*)&h;
        }
      }
    }
  }
}

extern "C" void kernel_launch(void* const* d_in, const int* in_sizes, int n_in,
                              void* d_out, int out_size, void* d_ws, size_t ws_size,
                              hipStream_t stream) {
  const float* features = (const float*)d_in[0];
  const float* W1 = (const float*)d_in[1];
  const float* b1 = (const float*)d_in[2];
  const float* W2 = (const float*)d_in[3];
  const float* b2 = (const float*)d_in[4];
  const int* ei = (const int*)d_in[5];
  float* out = (float*)d_out;

  char* ws = (char*)d_ws;
  size_t off = 0;
  auto alloc = [&](size_t bytes) -> void* {
    void* p = ws + off;
    off += (bytes + 255) & ~(size_t)255;
    return p;
  };
  float* onorm  = (float*)alloc((size_t)NNODES * 4);
  float* inorm  = (float*)alloc((size_t)NNODES * 4);
  int* din      = (int*)alloc((size_t)NNODES * 4);
  int* row_ptr  = (int*)alloc((size_t)(NNODES + 1) * 4);
  int* csr_src  = (int*)alloc((size_t)NEDGES * 4);
  int* blocksums = (int*)alloc((size_t)SCAN_NB * 4);
  int* blockoffs = (int*)alloc((size_t)SCAN_NB * 4);
  unsigned short* featb = (unsigned short*)alloc((size_t)NNODES * FIN * 2);
  unsigned short* aggF  = (unsigned short*)alloc((size_t)NNODES * FIN * 2);
  __bf16* h1  = (__bf16*)alloc((size_t)NNODES * FHID * 2);   // 38.4 MB
  __bf16* h2s = (__bf16*)alloc((size_t)NNODES * FOUT * 2);
  __bf16* W1t = (__bf16*)alloc((size_t)FIN * FHID * 2);
  __bf16* W2t = (__bf16*)alloc((size_t)FHID * FOUT * 2);
  (void)ws_size; (void)n_in; (void)in_sizes; (void)out_size;

  // hist scratch aliases h1 (dead until gemm1, which runs after fill):
  // psrc 12.8 MB | pdst 12.8 MB | rank 1.6 MB  (total 27.2 MB < 38.4 MB)
  unsigned* psrc = (unsigned*)h1;
  unsigned* pdst = psrc + (size_t)HB * HW;
  unsigned short* rank = (unsigned short*)(pdst + (size_t)HB * HW);

  // graph preprocessing: LDS histograms (no global atomics), fused norms,
  // exclusive scan, rank-based atomic-free CSR fill
  hist_kernel<<<dim3(HB, 2), 1024, 0, stream>>>(ei, psrc, pdst, rank);
  reduce_hist<<<(HW + 255) / 256, 256, 0, stream>>>(psrc, pdst, din, onorm, inorm);
  scan_part1<<<SCAN_NB, 256, 0, stream>>>(din, blocksums);
  scan_mid<<<1, 64, 0, stream>>>(blocksums, blockoffs);
  scan_part2<<<SCAN_NB, 256, 0, stream>>>(din, blockoffs, row_ptr);
  fill_kernel<<<(NEDGES + 255) / 256, 256, 0, stream>>>(ei, rank, pdst, row_ptr, csr_src);

  // converts (featb = onorm-prescaled bf16 features; W1/W2 transposed bf16)
  cvt_feat_kernel<<<(NNODES * FIN / 4 + 255) / 256, 256, 0, stream>>>(
      features, onorm, featb, NNODES * FIN / 4);
  wt_both<<<(FIN * FHID + FHID * FOUT + 255) / 256, 256, 0, stream>>>(W1, W2, W1t, W2t);

  // conv1: aggregate then transform (+bias, relu)
  agg1_kernel<<<(NNODES + 3) / 4, 256, 0, stream>>>(
      row_ptr, csr_src, inorm, featb, aggF);
  gemm_bf16<<<dim3((NNODES + 127) / 128, FHID / 128), 256, 0, stream>>>(
      (const __bf16*)aggF, W1t, b1, nullptr, h1, NNODES, FHID, FIN, 1);

  // conv2: transform (epilogue prescales rows by onorm) then aggregate (+b2)
  gemm_bf16<<<dim3((NNODES + 127) / 128, FOUT / 128), 256, 0, stream>>>(
      h1, W2t, nullptr, onorm, h2s, NNODES, FOUT, FHID, 0);
  agg2_kernel<<<(NNODES + 3) / 4, 256, 0, stream>>>(
      row_ptr, csr_src, inorm, (const unsigned short*)h2s, b2, out);
}